// Round 20
// baseline (132.337 us; speedup 1.0000x reference)
//
#include <hip/hip_runtime.h>
#include <hip/hip_bf16.h>

typedef __attribute__((ext_vector_type(8))) short bf16x8;
typedef __attribute__((ext_vector_type(4))) float f32x4;
typedef __attribute__((ext_vector_type(16))) float f32x16;
typedef __attribute__((ext_vector_type(2))) float f32x2;
typedef unsigned short u16;

#define Bc   2
#define Sc   2048
#define Dc   1024
#define Hc   16
#define HDc  64
#define ROTc 32
#define Mrows 4096  // B*S

__device__ __forceinline__ u16 f2bf(float x) {
  union { float f; unsigned u; } v{x};
  unsigned r = v.u + 0x7fffu + ((v.u >> 16) & 1u);
  return (u16)(r >> 16);
}
__device__ __forceinline__ float bf2f(u16 x) {
  union { unsigned u; float f; } v{(unsigned)x << 16};
  return v.f;
}
__device__ __forceinline__ unsigned cvtpk(float a, float b) {
  unsigned r;
  asm("v_cvt_pk_bf16_f32 %0, %1, %2" : "=v"(r) : "v"(a), "v"(b));
  return r;
}
__device__ __forceinline__ f32x2 pmax2(f32x2 a, f32x2 b) {
  f32x2 r;
  r.x = fmaxf(a.x, b.x);
  r.y = fmaxf(a.y, b.y);
  return r;
}

__device__ __forceinline__ void gload_lds16(const void* g, void* l) {
  __builtin_amdgcn_global_load_lds(
      (const __attribute__((address_space(1))) void*)g,
      (__attribute__((address_space(3))) void*)l, 16, 0, 0);
}

// ---------------- f32 -> bf16 conversion (hidden + 4 weights in one grid) --
__global__ void cvt_all(const float* __restrict__ h, const float* __restrict__ q,
                        const float* __restrict__ k, const float* __restrict__ v,
                        const float* __restrict__ o,
                        u16* __restrict__ hb, u16* __restrict__ qb, u16* __restrict__ kb,
                        u16* __restrict__ vb, u16* __restrict__ ob) {
  size_t i = ((size_t)blockIdx.x * 256 + threadIdx.x) * 4;
  const float* s;
  u16* d;
  size_t off;
  if (i < (size_t)Mrows * Dc) {
    s = h; d = hb; off = i;
  } else {
    size_t j = i - (size_t)Mrows * Dc;
    int w = (int)(j >> 20);            // 1M elements per weight
    off = j & ((1u << 20) - 1);
    s = (w == 0) ? q : (w == 1) ? k : (w == 2) ? v : o;
    d = (w == 0) ? qb : (w == 1) ? kb : (w == 2) ? vb : ob;
  }
  float4 val = *reinterpret_cast<const float4*>(s + off);
  u16 r0 = f2bf(val.x), r1 = f2bf(val.y), r2 = f2bf(val.z), r3 = f2bf(val.w);
  ushort4 outv = {r0, r1, r2, r3};
  *reinterpret_cast<ushort4*>(d + off) = outv;
}

// ---------------- fused QKV NT GEMM + RoPE epilogue, BK=64, grid (32,24) --
// (r19 verified: BK=64 halves step count; slot swizzle proven)
__global__ void gemm_qkv(const u16* __restrict__ A, const u16* __restrict__ W0,
                         const u16* __restrict__ W1, const u16* __restrict__ W2,
                         const float* __restrict__ freqs,
                         u16* __restrict__ Qo, u16* __restrict__ Ko,
                         u16* __restrict__ Vo) {
  __shared__ u16 As[128 * 64];
  __shared__ u16 Bs[128 * 64];
  const int by = blockIdx.y;
  const int wsel = by >> 3;
  const int n0 = (by & 7) * 128;
  const int m0 = blockIdx.x * 128;
  const u16* Bm = (wsel == 0) ? W0 : (wsel == 1) ? W1 : W2;
  const int t = threadIdx.x;
  const int w = t >> 6;
  const int lane = t & 63;
  const int wm = w >> 1, wn = w & 1;
  const int c = lane & 15, g = lane >> 4;
  const int sr = t >> 3;
  const int skoff = ((t & 7) ^ (sr & 7)) * 8;

  f32x4 acc[4][4] = {};

  const u16* ag = A + (size_t)(m0 + sr) * Dc + skoff;
  const u16* bg = Bm + (size_t)(n0 + sr) * Dc + skoff;
  const int ldst = w * 512;  // wave-uniform base per site (u16)

  for (int k0 = 0; k0 < Dc; k0 += 64) {
#pragma unroll
    for (int site = 0; site < 4; ++site) {
      gload_lds16(ag + k0 + (size_t)(site * 32) * Dc, &As[site * 2048 + ldst]);
      gload_lds16(bg + k0 + (size_t)(site * 32) * Dc, &Bs[site * 2048 + ldst]);
    }
    __syncthreads();
#pragma unroll
    for (int sub = 0; sub < 2; ++sub) {
      bf16x8 a[4], b[4];
#pragma unroll
      for (int f = 0; f < 4; ++f) {
        const int row = wm * 64 + f * 16 + c;
        const int p = ((sub * 4 + g) ^ (c & 7)) * 8;
        a[f] = *(const bf16x8*)&As[row * 64 + p];
        const int rowb = wn * 64 + f * 16 + c;
        b[f] = *(const bf16x8*)&Bs[rowb * 64 + p];
      }
      __builtin_amdgcn_s_setprio(1);
#pragma unroll
      for (int fm = 0; fm < 4; ++fm)
#pragma unroll
        for (int fn = 0; fn < 4; ++fn)
          acc[fm][fn] =
              __builtin_amdgcn_mfma_f32_16x16x32_bf16(a[fm], b[fn], acc[fm][fn], 0, 0, 0);
      __builtin_amdgcn_s_setprio(0);
    }
    __syncthreads();
  }

  u16* dst = (wsel == 0) ? Qo : (wsel == 1) ? Ko : Vo;
  const float qsc = (wsel == 0) ? 0.125f * 1.44269504f : 1.0f;  // HD^-0.5*log2e
  const int codd = c & 1;
#pragma unroll
  for (int fm = 0; fm < 4; ++fm)
#pragma unroll
    for (int fn = 0; fn < 4; ++fn)
#pragma unroll
      for (int r = 0; r < 4; ++r) {
        const int m = m0 + wm * 64 + fm * 16 + g * 4 + r;
        const int n = n0 + wn * 64 + fn * 16 + c;
        float v = acc[fm][fn][r];
        const int b = m >> 11, s = m & (Sc - 1);
        const int hh = n >> 6, d = n & 63;
        size_t idx2;
        if (wsel < 2) {
          const float other = __shfl_xor(v, 1);
          const float2 f = reinterpret_cast<const float2*>(freqs)[s * ROTc + (d >> 1)];
          v = codd ? (v * f.x + other * f.y) : (v * f.x - other * f.y);
          v *= qsc;
          idx2 = (((size_t)(b * Hc + hh) * Sc) + s) * HDc + d;
        } else {
          idx2 = ((size_t)(b * Hc + hh) * HDc + d) * Sc + s;
        }
        dst[idx2] = f2bf(v);
      }
}

// ---------------- final GEMM: out = ab @ wo^T, BK=64, grid (64,8) ---------
__global__ void gemm_out(const u16* __restrict__ A, const u16* __restrict__ Bm,
                         float* __restrict__ C) {
  __shared__ u16 As[64 * 64];
  __shared__ u16 Bs[128 * 64];
  const int m0 = blockIdx.x * 64;
  const int n0 = blockIdx.y * 128;
  const int t = threadIdx.x;
  const int w = t >> 6;
  const int lane = t & 63;
  const int wm = w >> 1, wn = w & 1;  // wave tile 32x64
  const int c = lane & 15, g = lane >> 4;
  const int sr = t >> 3;
  const int skoff = ((t & 7) ^ (sr & 7)) * 8;

  f32x4 acc[2][4] = {};

  const u16* ag = A + (size_t)(m0 + sr) * Dc + skoff;
  const u16* bg = Bm + (size_t)(n0 + sr) * Dc + skoff;
  const int ldst = w * 512;

  for (int k0 = 0; k0 < Dc; k0 += 64) {
#pragma unroll
    for (int site = 0; site < 2; ++site)
      gload_lds16(ag + k0 + (size_t)(site * 32) * Dc, &As[site * 2048 + ldst]);
#pragma unroll
    for (int site = 0; site < 4; ++site)
      gload_lds16(bg + k0 + (size_t)(site * 32) * Dc, &Bs[site * 2048 + ldst]);
    __syncthreads();
#pragma unroll
    for (int sub = 0; sub < 2; ++sub) {
      bf16x8 a[2], b[4];
      const int p = ((sub * 4 + g) ^ (c & 7)) * 8;
#pragma unroll
      for (int f = 0; f < 2; ++f)
        a[f] = *(const bf16x8*)&As[(wm * 32 + f * 16 + c) * 64 + p];
#pragma unroll
      for (int f = 0; f < 4; ++f)
        b[f] = *(const bf16x8*)&Bs[(wn * 64 + f * 16 + c) * 64 + p];
      __builtin_amdgcn_s_setprio(1);
#pragma unroll
      for (int fm = 0; fm < 2; ++fm)
#pragma unroll
        for (int fn = 0; fn < 4; ++fn)
          acc[fm][fn] =
              __builtin_amdgcn_mfma_f32_16x16x32_bf16(a[fm], b[fn], acc[fm][fn], 0, 0, 0);
      __builtin_amdgcn_s_setprio(0);
    }
    __syncthreads();
  }

#pragma unroll
  for (int fm = 0; fm < 2; ++fm)
#pragma unroll
    for (int fn = 0; fn < 4; ++fn)
#pragma unroll
      for (int r = 0; r < 4; ++r) {
        const int m = m0 + wm * 32 + fm * 16 + g * 4 + r;
        const int n = n0 + wn * 64 + fn * 16 + c;
        C[(size_t)m * Dc + n] = acc[fm][fn][r];
      }
}

// ---------------- flash attention: in-block split-KV, 4 blocks/CU ---------
// 256 thr = 4 waves = 2 kv-groups x 2 waves; block covers 64 q-rows; grid
// 1024 = 32 bh x 32 q-tiles -> 4 blocks/CU (was 2: grid-capped).  4
// independent barrier domains cover each other's stage stalls.  LDS layout,
// tile loop, softmax, PV, merge identical to r13/r19-verified kernel; only
// thread->group mapping + staging loop (4 j-sites per thread) change.
// v_permlane32_swap BANNED (r5+r10); all exchanges via __shfl_xor.
__global__ __launch_bounds__(256, 4) void flash_attn(
    const u16* __restrict__ Q, const u16* __restrict__ Kb,
    const u16* __restrict__ Vt, u16* __restrict__ Ob) {
  __shared__ u16 smem[18432];  // K: grp*4096 ; V: 8192+grp*4096 ; 36KB total
  const int orig = blockIdx.x;
  const int wg = (orig & 7) * 128 + (orig >> 3);  // bijective XCD chunking
  const int bh = wg >> 5;
  const int q0 = (wg & 31) * 64;
  const int t = threadIdx.x, w = t >> 6, lane = t & 63;
  const int grp = w >> 1, wl = w & 1;
  const int ts = t & 127;  // thread index within group (2 waves)
  const int l31 = lane & 31, hi = lane >> 5;
  const int sr2 = ts >> 4;           // 0..7
  const int rsw = (l31 & 15);        // read-side slot swizzle

  const u16* Qp = Q + (size_t)bh * Sc * HDc;
  const u16* Kp = Kb + (size_t)bh * Sc * HDc;
  const u16* Vp = Vt + (size_t)bh * HDc * Sc;
  u16* const Kg = smem + grp * 4096;
  u16* const Vg = smem + 8192 + grp * 4096;

  const int q = q0 + wl * 32 + l31;
  bf16x8 aq[4];
#pragma unroll
  for (int kd = 0; kd < 4; ++kd)
    aq[kd] = *(const bf16x8*)(Qp + (size_t)q * HDc + kd * 16 + hi * 8);

  float m_run = -1e30f, l_run = 0.f;
  f32x16 o0 = {}, o1 = {};

  // staging: 128 thr/group, 4 sites each; phys row = j*8+sr2, slot = ts&15;
  // logical slot su = (ts&15)^(phys&15) -> src row = phys + (su>>3)*32,
  // src col = (su&7)*8.  Same involution as r13 (linear dest, swz source).
  auto STAGE = [&](int tile) {
    const int base = grp * 1024 + tile * 64;
#pragma unroll
    for (int j = 0; j < 4; ++j) {
      const int ph = j * 8 + sr2;                 // phys row 0..31
      const int su = (ts & 15) ^ (ph & 15);
      const int srcr = ph + ((su >> 3) << 5);     // src row 0..63
      const int sd8 = (su & 7) * 8;               // src col (u16)
      gload_lds16(Kp + (size_t)(base + srcr) * HDc + sd8,
                  Kg + j * 1024 + wl * 512);
      gload_lds16(Vp + (size_t)srcr * Sc + base + sd8,
                  Vg + j * 1024 + wl * 512);
    }
  };

  for (int tt = 0; tt < 16; ++tt) {
    STAGE(tt);
    __syncthreads();  // stage landed (barrier drains vmcnt)
    // QK^T (swapped): s0 rows = kv l31 ; s1 rows = kv 32+l31 ; cols = q
    f32x16 s0 = {}, s1 = {};
    __builtin_amdgcn_s_setprio(1);
#pragma unroll
    for (int kd = 0; kd < 4; ++kd) {
      const int u0 = kd * 2 + hi;
      bf16x8 a0 = *(const bf16x8*)&Kg[l31 * 128 + (u0 ^ rsw) * 8];
      bf16x8 a1 = *(const bf16x8*)&Kg[l31 * 128 + ((u0 + 8) ^ rsw) * 8];
      s0 = __builtin_amdgcn_mfma_f32_32x32x16_bf16(a0, aq[kd], s0, 0, 0, 0);
      s1 = __builtin_amdgcn_mfma_f32_32x32x16_bf16(a1, aq[kd], s1, 0, 0, 0);
    }
    __builtin_amdgcn_s_setprio(0);
    // packed-f32 row max (lane-local + one cross-half shuffle)
    f32x2 t4[4];
#pragma unroll
    for (int i = 0; i < 4; ++i) {
      f32x2 e0; e0.x = s0[2 * i]; e0.y = s0[2 * i + 1];
      f32x2 e1; e1.x = s0[2 * i + 8]; e1.y = s0[2 * i + 9];
      f32x2 e2; e2.x = s1[2 * i]; e2.y = s1[2 * i + 1];
      f32x2 e3; e3.x = s1[2 * i + 8]; e3.y = s1[2 * i + 9];
      t4[i] = pmax2(pmax2(e0, e1), pmax2(e2, e3));
    }
    f32x2 tp = pmax2(pmax2(t4[0], t4[1]), pmax2(t4[2], t4[3]));
    float mt = fmaxf(tp.x, tp.y);
    mt = fmaxf(mt, __shfl_xor(mt, 32));
    const bool skip = __all(mt <= m_run + 8.0f);
    if (!skip) {
      const float mn2 = fmaxf(m_run, mt);
      const float scl = __builtin_amdgcn_exp2f(m_run - mn2);
      m_run = mn2;
      l_run *= scl;
      o0 *= scl;
      o1 *= scl;
    }
    const float mn = m_run;
#pragma unroll
    for (int r = 0; r < 16; ++r) {
      s0[r] = __builtin_amdgcn_exp2f(s0[r] - mn);
      s1[r] = __builtin_amdgcn_exp2f(s1[r] - mn);
    }
    f32x2 ac;
    ac.x = 0.f; ac.y = 0.f;
#pragma unroll
    for (int i = 0; i < 8; ++i) {
      f32x2 e0; e0.x = s0[2 * i]; e0.y = s0[2 * i + 1];
      f32x2 e1; e1.x = s1[2 * i]; e1.y = s1[2 * i + 1];
      ac += e0 + e1;
    }
    float rs = ac.x + ac.y;
    rs += __shfl_xor(rs, 32);
    l_run += rs;
    // pack P to bf16 pairs: pk[kb][2B+s] covers kv = kb*32+8B+4*hi+2s(+1)
    unsigned pk0[8], pk1[8];
#pragma unroll
    for (int B = 0; B < 4; ++B)
#pragma unroll
      for (int s2 = 0; s2 < 2; ++s2) {
        pk0[B * 2 + s2] = cvtpk(s0[4 * B + 2 * s2], s0[4 * B + 2 * s2 + 1]);
        pk1[B * 2 + s2] = cvtpk(s1[4 * B + 2 * s2], s1[4 * B + 2 * s2 + 1]);
      }
    // PV: O = mfma(A=V^T, B=P); V fragments read inline from LDS
#pragma unroll
    for (int ks = 0; ks < 4; ++ks) {
      const unsigned* pk = (ks >> 1) ? pk1 : pk0;
      const int m2 = (ks & 1) * 4;
      const unsigned A0 = pk[m2 + 0], A1 = pk[m2 + 1];
      const unsigned B0 = pk[m2 + 2], B1 = pk[m2 + 3];
      const unsigned L0 = hi ? B0 : A0, L1 = hi ? B1 : A1;
      const unsigned R0 = hi ? A0 : B0, R1 = hi ? A1 : B1;
      const unsigned X0 = __shfl_xor(R0, 32), X1 = __shfl_xor(R1, 32);
      union { unsigned u[4]; bf16x8 v; } bp;
      bp.u[0] = hi ? X0 : L0;
      bp.u[1] = hi ? X1 : L1;
      bp.u[2] = hi ? L0 : X0;
      bp.u[3] = hi ? L1 : X1;
      const int uv = ks * 2 + hi;
      bf16x8 va0 = *(const bf16x8*)&Vg[l31 * 128 + (uv ^ rsw) * 8];
      bf16x8 va1 = *(const bf16x8*)&Vg[l31 * 128 + ((uv + 8) ^ rsw) * 8];
      __builtin_amdgcn_s_setprio(1);
      o0 = __builtin_amdgcn_mfma_f32_32x32x16_bf16(va0, bp.v, o0, 0, 0, 0);
      o1 = __builtin_amdgcn_mfma_f32_32x32x16_bf16(va1, bp.v, o1, 0, 0, 0);
      __builtin_amdgcn_s_setprio(0);
    }
    __syncthreads();  // all reads of this tile done before next stage
  }

  // ---- in-LDS merge: group 1 -> LDS (raw O + m + l), group 0 combines ----
  float* fl = reinterpret_cast<float*>(smem);
  const int slot = (wl * 64 + lane) * 34;  // 128 rows x 34 floats = 17.4KB
  if (grp == 1) {
#pragma unroll
    for (int j = 0; j < 16; ++j) fl[slot + j] = o0[j];
#pragma unroll
    for (int j = 0; j < 16; ++j) fl[slot + 16 + j] = o1[j];
    fl[slot + 32] = m_run;
    fl[slot + 33] = l_run;
  }
  __syncthreads();
  if (grp == 0) {
    const float mB = fl[slot + 32], lB = fl[slot + 33];
    const float mx = fmaxf(m_run, mB);
    const float sA = __builtin_amdgcn_exp2f(m_run - mx);
    const float sB = __builtin_amdgcn_exp2f(mB - mx);
    const float rd = 1.0f / (l_run * sA + lB * sB);
    const float cA = sA * rd, cB = sB * rd;
    const int b = bh >> 4, hh = bh & 15;
    u16* orow = Ob + ((size_t)b * Sc + q) * Dc + hh * HDc;
#pragma unroll
    for (int B2 = 0; B2 < 4; ++B2) {
      const float v0 = o0[4 * B2 + 0] * cA + fl[slot + 4 * B2 + 0] * cB;
      const float v1 = o0[4 * B2 + 1] * cA + fl[slot + 4 * B2 + 1] * cB;
      const float v2 = o0[4 * B2 + 2] * cA + fl[slot + 4 * B2 + 2] * cB;
      const float v3 = o0[4 * B2 + 3] * cA + fl[slot + 4 * B2 + 3] * cB;
      uint2 pv;
      pv.x = cvtpk(v0, v1);
      pv.y = cvtpk(v2, v3);
      *reinterpret_cast<uint2*>(orow + 8 * B2 + 4 * hi) = pv;
    }
#pragma unroll
    for (int B2 = 0; B2 < 4; ++B2) {
      const float v0 = o1[4 * B2 + 0] * cA + fl[slot + 16 + 4 * B2 + 0] * cB;
      const float v1 = o1[4 * B2 + 1] * cA + fl[slot + 16 + 4 * B2 + 1] * cB;
      const float v2 = o1[4 * B2 + 2] * cA + fl[slot + 16 + 4 * B2 + 2] * cB;
      const float v3 = o1[4 * B2 + 3] * cA + fl[slot + 16 + 4 * B2 + 3] * cB;
      uint2 pv;
      pv.x = cvtpk(v0, v1);
      pv.y = cvtpk(v2, v3);
      *reinterpret_cast<uint2*>(orow + 32 + 8 * B2 + 4 * hi) = pv;
    }
  }
}

extern "C" void kernel_launch(void* const* d_in, const int* in_sizes, int n_in,
                              void* d_out, int out_size, void* d_ws, size_t ws_size,
                              hipStream_t stream) {
  (void)in_sizes; (void)n_in; (void)out_size; (void)ws_size;
  const float* hidden = (const float*)d_in[0];
  const float* freqs = (const float*)d_in[1];
  const float* wq = (const float*)d_in[2];
  const float* wk = (const float*)d_in[3];
  const float* wv = (const float*)d_in[4];
  const float* wo = (const float*)d_in[5];
  float* out = (float*)d_out;

  char* ws = (char*)d_ws;
  const size_t MB8 = (size_t)Mrows * Dc * 2;  // 8 MiB
  const size_t WB = (size_t)Dc * Dc * 2;      // 2 MiB
  u16* hb = (u16*)ws;  ws += MB8;
  u16* wqb = (u16*)ws; ws += WB;
  u16* wkb = (u16*)ws; ws += WB;
  u16* wvb = (u16*)ws; ws += WB;
  u16* wob = (u16*)ws; ws += WB;
  u16* qb = (u16*)ws;  ws += MB8;
  u16* kb = (u16*)ws;  ws += MB8;
  u16* vtb = (u16*)ws; ws += MB8;
  u16* ab = (u16*)ws;  ws += MB8;

  cvt_all<<<8192, 256, 0, stream>>>(hidden, wq, wk, wv, wo, hb, wqb, wkb, wvb, wob);
  gemm_qkv<<<dim3(32, 24), 256, 0, stream>>>(hb, wqb, wkb, wvb, freqs, qb, kb, vtb);
  flash_attn<<<1024, 256, 0, stream>>>(qb, kb, vtb, ab);
  gemm_out<<<dim3(64, 8), 256, 0, stream>>>(ab, wob, out);
}

// Round 22
// 130.753 us; speedup vs baseline: 1.0121x; 1.0121x over previous
//
#include <hip/hip_runtime.h>
#include <hip/hip_bf16.h>

typedef __attribute__((ext_vector_type(8))) short bf16x8;
typedef __attribute__((ext_vector_type(4))) float f32x4;
typedef __attribute__((ext_vector_type(16))) float f32x16;
typedef __attribute__((ext_vector_type(2))) float f32x2;
typedef unsigned short u16;

#define Bc   2
#define Sc   2048
#define Dc   1024
#define Hc   16
#define HDc  64
#define ROTc 32
#define Mrows 4096  // B*S

__device__ __forceinline__ u16 f2bf(float x) {
  union { float f; unsigned u; } v{x};
  unsigned r = v.u + 0x7fffu + ((v.u >> 16) & 1u);
  return (u16)(r >> 16);
}
__device__ __forceinline__ float bf2f(u16 x) {
  union { unsigned u; float f; } v{(unsigned)x << 16};
  return v.f;
}
__device__ __forceinline__ unsigned cvtpk(float a, float b) {
  unsigned r;
  asm("v_cvt_pk_bf16_f32 %0, %1, %2" : "=v"(r) : "v"(a), "v"(b));
  return r;
}
__device__ __forceinline__ f32x2 pmax2(f32x2 a, f32x2 b) {
  f32x2 r;
  r.x = fmaxf(a.x, b.x);
  r.y = fmaxf(a.y, b.y);
  return r;
}

__device__ __forceinline__ void gload_lds16(const void* g, void* l) {
  __builtin_amdgcn_global_load_lds(
      (const __attribute__((address_space(1))) void*)g,
      (__attribute__((address_space(3))) void*)l, 16, 0, 0);
}

// ---------------- f32 -> bf16 conversion (hidden + 4 weights in one grid) --
__global__ void cvt_all(const float* __restrict__ h, const float* __restrict__ q,
                        const float* __restrict__ k, const float* __restrict__ v,
                        const float* __restrict__ o,
                        u16* __restrict__ hb, u16* __restrict__ qb, u16* __restrict__ kb,
                        u16* __restrict__ vb, u16* __restrict__ ob) {
  size_t i = ((size_t)blockIdx.x * 256 + threadIdx.x) * 4;
  const float* s;
  u16* d;
  size_t off;
  if (i < (size_t)Mrows * Dc) {
    s = h; d = hb; off = i;
  } else {
    size_t j = i - (size_t)Mrows * Dc;
    int w = (int)(j >> 20);            // 1M elements per weight
    off = j & ((1u << 20) - 1);
    s = (w == 0) ? q : (w == 1) ? k : (w == 2) ? v : o;
    d = (w == 0) ? qb : (w == 1) ? kb : (w == 2) ? vb : ob;
  }
  float4 val = *reinterpret_cast<const float4*>(s + off);
  u16 r0 = f2bf(val.x), r1 = f2bf(val.y), r2 = f2bf(val.z), r3 = f2bf(val.w);
  ushort4 outv = {r0, r1, r2, r3};
  *reinterpret_cast<ushort4*>(d + off) = outv;
}

// ---------------- fused QKV NT GEMM + RoPE epilogue, BK=128, grid (32,24) -
// BK=128: 16 gloads/thread in flight per step, 8 barriers total (Little's-
// law fix for the outstanding-loads-limited staging; r19 BK 32->64 ~null).
// LDS 64KB -> 2 blocks/CU.  Swizzle: row = 16 slots of 16B; staging thread
// t -> dest u16 site*2048 + t*8 (phys row t>>4, slot t&15); source k-chunk
// su = (t&15)^(t>>4); reader of chunk L at row r uses slot L^(r&15)=L^c.
// r21 NaN bug: ldst was w*1024; per-wave staging is 64 thr x 8 u16 = w*512.
__global__ void gemm_qkv(const u16* __restrict__ A, const u16* __restrict__ W0,
                         const u16* __restrict__ W1, const u16* __restrict__ W2,
                         const float* __restrict__ freqs,
                         u16* __restrict__ Qo, u16* __restrict__ Ko,
                         u16* __restrict__ Vo) {
  __shared__ u16 As[128 * 128];
  __shared__ u16 Bs[128 * 128];
  const int by = blockIdx.y;
  const int wsel = by >> 3;
  const int n0 = (by & 7) * 128;
  const int m0 = blockIdx.x * 128;
  const u16* Bm = (wsel == 0) ? W0 : (wsel == 1) ? W1 : W2;
  const int t = threadIdx.x;
  const int w = t >> 6;
  const int lane = t & 63;
  const int wm = w >> 1, wn = w & 1;
  const int c = lane & 15, g = lane >> 4;
  const int srr = t >> 4;                       // staging row within site 0..15
  const int su = (t & 15) ^ srr;                // logical k-chunk (site-indep)
  const int skoff = su * 8;                     // source k offset (u16)

  f32x4 acc[4][4] = {};

  const u16* ag = A + (size_t)(m0 + srr) * Dc + skoff;
  const u16* bg = Bm + (size_t)(n0 + srr) * Dc + skoff;
  const int ldst = w * 512;  // wave-uniform base (64 thr x 16B = 512 u16)

  for (int k0 = 0; k0 < Dc; k0 += 128) {
#pragma unroll
    for (int site = 0; site < 8; ++site)
      gload_lds16(ag + k0 + (size_t)(site * 16) * Dc, &As[site * 2048 + ldst]);
#pragma unroll
    for (int site = 0; site < 8; ++site)
      gload_lds16(bg + k0 + (size_t)(site * 16) * Dc, &Bs[site * 2048 + ldst]);
    __syncthreads();
#pragma unroll
    for (int sub = 0; sub < 4; ++sub) {
      bf16x8 a[4], b[4];
#pragma unroll
      for (int f = 0; f < 4; ++f) {
        const int row = wm * 64 + f * 16 + c;   // row&15 == c
        const int p = ((sub * 4 + g) ^ c) * 8;
        a[f] = *(const bf16x8*)&As[row * 128 + p];
        const int rowb = wn * 64 + f * 16 + c;
        b[f] = *(const bf16x8*)&Bs[rowb * 128 + p];
      }
      __builtin_amdgcn_s_setprio(1);
#pragma unroll
      for (int fm = 0; fm < 4; ++fm)
#pragma unroll
        for (int fn = 0; fn < 4; ++fn)
          acc[fm][fn] =
              __builtin_amdgcn_mfma_f32_16x16x32_bf16(a[fm], b[fn], acc[fm][fn], 0, 0, 0);
      __builtin_amdgcn_s_setprio(0);
    }
    __syncthreads();
  }

  u16* dst = (wsel == 0) ? Qo : (wsel == 1) ? Ko : Vo;
  const float qsc = (wsel == 0) ? 0.125f * 1.44269504f : 1.0f;  // HD^-0.5*log2e
  const int codd = c & 1;
#pragma unroll
  for (int fm = 0; fm < 4; ++fm)
#pragma unroll
    for (int fn = 0; fn < 4; ++fn)
#pragma unroll
      for (int r = 0; r < 4; ++r) {
        const int m = m0 + wm * 64 + fm * 16 + g * 4 + r;
        const int n = n0 + wn * 64 + fn * 16 + c;
        float v = acc[fm][fn][r];
        const int b = m >> 11, s = m & (Sc - 1);
        const int hh = n >> 6, d = n & 63;
        size_t idx2;
        if (wsel < 2) {
          const float other = __shfl_xor(v, 1);
          const float2 f = reinterpret_cast<const float2*>(freqs)[s * ROTc + (d >> 1)];
          v = codd ? (v * f.x + other * f.y) : (v * f.x - other * f.y);
          v *= qsc;
          idx2 = (((size_t)(b * Hc + hh) * Sc) + s) * HDc + d;
        } else {
          idx2 = ((size_t)(b * Hc + hh) * HDc + d) * Sc + s;
        }
        dst[idx2] = f2bf(v);
      }
}

// ---------------- final GEMM: out = ab @ wo^T, BK=64, grid (64,8) ---------
__global__ void gemm_out(const u16* __restrict__ A, const u16* __restrict__ Bm,
                         float* __restrict__ C) {
  __shared__ u16 As[64 * 64];
  __shared__ u16 Bs[128 * 64];
  const int m0 = blockIdx.x * 64;
  const int n0 = blockIdx.y * 128;
  const int t = threadIdx.x;
  const int w = t >> 6;
  const int lane = t & 63;
  const int wm = w >> 1, wn = w & 1;  // wave tile 32x64
  const int c = lane & 15, g = lane >> 4;
  const int sr = t >> 3;
  const int skoff = ((t & 7) ^ (sr & 7)) * 8;

  f32x4 acc[2][4] = {};

  const u16* ag = A + (size_t)(m0 + sr) * Dc + skoff;
  const u16* bg = Bm + (size_t)(n0 + sr) * Dc + skoff;
  const int ldst = w * 512;

  for (int k0 = 0; k0 < Dc; k0 += 64) {
#pragma unroll
    for (int site = 0; site < 2; ++site)
      gload_lds16(ag + k0 + (size_t)(site * 32) * Dc, &As[site * 2048 + ldst]);
#pragma unroll
    for (int site = 0; site < 4; ++site)
      gload_lds16(bg + k0 + (size_t)(site * 32) * Dc, &Bs[site * 2048 + ldst]);
    __syncthreads();
#pragma unroll
    for (int sub = 0; sub < 2; ++sub) {
      bf16x8 a[2], b[4];
      const int p = ((sub * 4 + g) ^ (c & 7)) * 8;
#pragma unroll
      for (int f = 0; f < 2; ++f)
        a[f] = *(const bf16x8*)&As[(wm * 32 + f * 16 + c) * 64 + p];
#pragma unroll
      for (int f = 0; f < 4; ++f)
        b[f] = *(const bf16x8*)&Bs[(wn * 64 + f * 16 + c) * 64 + p];
      __builtin_amdgcn_s_setprio(1);
#pragma unroll
      for (int fm = 0; fm < 2; ++fm)
#pragma unroll
        for (int fn = 0; fn < 4; ++fn)
          acc[fm][fn] =
              __builtin_amdgcn_mfma_f32_16x16x32_bf16(a[fm], b[fn], acc[fm][fn], 0, 0, 0);
      __builtin_amdgcn_s_setprio(0);
    }
    __syncthreads();
  }

#pragma unroll
  for (int fm = 0; fm < 2; ++fm)
#pragma unroll
    for (int fn = 0; fn < 4; ++fn)
#pragma unroll
      for (int r = 0; r < 4; ++r) {
        const int m = m0 + wm * 32 + fm * 16 + g * 4 + r;
        const int n = n0 + wn * 64 + fn * 16 + c;
        C[(size_t)m * Dc + n] = acc[fm][fn][r];
      }
}

// ---------------- flash attention: in-block split-KV (r13/r19 proven) -----
// 512 thr = 2 groups x 4 waves; group g covers kv [g*1024, (g+1)*1024).
// Grid 512 = 2 blocks/CU.  (r20: halving block size doubled per-q staging
// traffic -> -10%; reverted.)  Single K/V buf per group, in-LDS LSE merge.
// v_permlane32_swap BANNED (r5+r10); all exchanges via __shfl_xor.
__global__ __launch_bounds__(512, 2) void flash_attn(
    const u16* __restrict__ Q, const u16* __restrict__ Kb,
    const u16* __restrict__ Vt, u16* __restrict__ Ob) {
  __shared__ u16 smem[18432];  // K: grp*4096 ; V: 8192+grp*4096 ; 36KB total
  const int orig = blockIdx.x;
  const int wg = (orig & 7) * 64 + (orig >> 3);  // bijective XCD chunking
  const int bh = wg >> 4;
  const int q0 = (wg & 15) * 128;
  const int t = threadIdx.x, w = t >> 6, lane = t & 63;
  const int grp = w >> 2, wl = w & 3;
  const int ts = t & 255;  // thread index within group
  const int l31 = lane & 31, hi = lane >> 5;
  const int sr = ts >> 4;
  const int su = (ts & 15) ^ (sr & 15);
  const int skv = sr + ((su >> 3) << 5);  // source kv (K) / d (V) row
  const int sd8 = (su & 7) * 8;           // source col offset (u16)
  const int rsw = (l31 & 15);             // read-side slot swizzle

  const u16* Qp = Q + (size_t)bh * Sc * HDc;
  const u16* Kp = Kb + (size_t)bh * Sc * HDc;
  const u16* Vp = Vt + (size_t)bh * HDc * Sc;
  u16* const Kg = smem + grp * 4096;
  u16* const Vg = smem + 8192 + grp * 4096;

  const int q = q0 + wl * 32 + l31;
  bf16x8 aq[4];
#pragma unroll
  for (int kd = 0; kd < 4; ++kd)
    aq[kd] = *(const bf16x8*)(Qp + (size_t)q * HDc + kd * 16 + hi * 8);

  float m_run = -1e30f, l_run = 0.f;
  f32x16 o0 = {}, o1 = {};

  auto STAGE = [&](int tile) {
    const int base = grp * 1024 + tile * 64;
    gload_lds16(Kp + (size_t)(base + skv) * HDc + sd8, Kg + wl * 512);
    gload_lds16(Kp + (size_t)(base + skv + 16) * HDc + sd8, Kg + 2048 + wl * 512);
    gload_lds16(Vp + (size_t)skv * Sc + base + sd8, Vg + wl * 512);
    gload_lds16(Vp + (size_t)(skv + 16) * Sc + base + sd8, Vg + 2048 + wl * 512);
  };

  for (int tt = 0; tt < 16; ++tt) {
    STAGE(tt);
    __syncthreads();  // stage landed (barrier drains vmcnt)
    f32x16 s0 = {}, s1 = {};
    __builtin_amdgcn_s_setprio(1);
#pragma unroll
    for (int kd = 0; kd < 4; ++kd) {
      const int u0 = kd * 2 + hi;
      bf16x8 a0 = *(const bf16x8*)&Kg[l31 * 128 + (u0 ^ rsw) * 8];
      bf16x8 a1 = *(const bf16x8*)&Kg[l31 * 128 + ((u0 + 8) ^ rsw) * 8];
      s0 = __builtin_amdgcn_mfma_f32_32x32x16_bf16(a0, aq[kd], s0, 0, 0, 0);
      s1 = __builtin_amdgcn_mfma_f32_32x32x16_bf16(a1, aq[kd], s1, 0, 0, 0);
    }
    __builtin_amdgcn_s_setprio(0);
    f32x2 t4[4];
#pragma unroll
    for (int i = 0; i < 4; ++i) {
      f32x2 e0; e0.x = s0[2 * i]; e0.y = s0[2 * i + 1];
      f32x2 e1; e1.x = s0[2 * i + 8]; e1.y = s0[2 * i + 9];
      f32x2 e2; e2.x = s1[2 * i]; e2.y = s1[2 * i + 1];
      f32x2 e3; e3.x = s1[2 * i + 8]; e3.y = s1[2 * i + 9];
      t4[i] = pmax2(pmax2(e0, e1), pmax2(e2, e3));
    }
    f32x2 tp = pmax2(pmax2(t4[0], t4[1]), pmax2(t4[2], t4[3]));
    float mt = fmaxf(tp.x, tp.y);
    mt = fmaxf(mt, __shfl_xor(mt, 32));
    const bool skip = __all(mt <= m_run + 8.0f);
    if (!skip) {
      const float mn2 = fmaxf(m_run, mt);
      const float scl = __builtin_amdgcn_exp2f(m_run - mn2);
      m_run = mn2;
      l_run *= scl;
      o0 *= scl;
      o1 *= scl;
    }
    const float mn = m_run;
#pragma unroll
    for (int r = 0; r < 16; ++r) {
      s0[r] = __builtin_amdgcn_exp2f(s0[r] - mn);
      s1[r] = __builtin_amdgcn_exp2f(s1[r] - mn);
    }
    f32x2 ac;
    ac.x = 0.f; ac.y = 0.f;
#pragma unroll
    for (int i = 0; i < 8; ++i) {
      f32x2 e0; e0.x = s0[2 * i]; e0.y = s0[2 * i + 1];
      f32x2 e1; e1.x = s1[2 * i]; e1.y = s1[2 * i + 1];
      ac += e0 + e1;
    }
    float rs = ac.x + ac.y;
    rs += __shfl_xor(rs, 32);
    l_run += rs;
    unsigned pk0[8], pk1[8];
#pragma unroll
    for (int B = 0; B < 4; ++B)
#pragma unroll
      for (int s2 = 0; s2 < 2; ++s2) {
        pk0[B * 2 + s2] = cvtpk(s0[4 * B + 2 * s2], s0[4 * B + 2 * s2 + 1]);
        pk1[B * 2 + s2] = cvtpk(s1[4 * B + 2 * s2], s1[4 * B + 2 * s2 + 1]);
      }
#pragma unroll
    for (int ks = 0; ks < 4; ++ks) {
      const unsigned* pk = (ks >> 1) ? pk1 : pk0;
      const int m2 = (ks & 1) * 4;
      const unsigned A0 = pk[m2 + 0], A1 = pk[m2 + 1];
      const unsigned B0 = pk[m2 + 2], B1 = pk[m2 + 3];
      const unsigned L0 = hi ? B0 : A0, L1 = hi ? B1 : A1;
      const unsigned R0 = hi ? A0 : B0, R1 = hi ? A1 : B1;
      const unsigned X0 = __shfl_xor(R0, 32), X1 = __shfl_xor(R1, 32);
      union { unsigned u[4]; bf16x8 v; } bp;
      bp.u[0] = hi ? X0 : L0;
      bp.u[1] = hi ? X1 : L1;
      bp.u[2] = hi ? L0 : X0;
      bp.u[3] = hi ? L1 : X1;
      const int uv = ks * 2 + hi;
      bf16x8 va0 = *(const bf16x8*)&Vg[l31 * 128 + (uv ^ rsw) * 8];
      bf16x8 va1 = *(const bf16x8*)&Vg[l31 * 128 + ((uv + 8) ^ rsw) * 8];
      __builtin_amdgcn_s_setprio(1);
      o0 = __builtin_amdgcn_mfma_f32_32x32x16_bf16(va0, bp.v, o0, 0, 0, 0);
      o1 = __builtin_amdgcn_mfma_f32_32x32x16_bf16(va1, bp.v, o1, 0, 0, 0);
      __builtin_amdgcn_s_setprio(0);
    }
    __syncthreads();  // all reads of this tile done before next stage
  }

  // ---- in-LDS merge: group 1 -> LDS (raw O + m + l), group 0 combines ----
  float* fl = reinterpret_cast<float*>(smem);
  const int slot = (wl * 64 + lane) * 34;
  if (grp == 1) {
#pragma unroll
    for (int j = 0; j < 16; ++j) fl[slot + j] = o0[j];
#pragma unroll
    for (int j = 0; j < 16; ++j) fl[slot + 16 + j] = o1[j];
    fl[slot + 32] = m_run;
    fl[slot + 33] = l_run;
  }
  __syncthreads();
  if (grp == 0) {
    const float mB = fl[slot + 32], lB = fl[slot + 33];
    const float mx = fmaxf(m_run, mB);
    const float sA = __builtin_amdgcn_exp2f(m_run - mx);
    const float sB = __builtin_amdgcn_exp2f(mB - mx);
    const float rd = 1.0f / (l_run * sA + lB * sB);
    const float cA = sA * rd, cB = sB * rd;
    const int b = bh >> 4, hh = bh & 15;
    u16* orow = Ob + ((size_t)b * Sc + q) * Dc + hh * HDc;
#pragma unroll
    for (int B2 = 0; B2 < 4; ++B2) {
      const float v0 = o0[4 * B2 + 0] * cA + fl[slot + 4 * B2 + 0] * cB;
      const float v1 = o0[4 * B2 + 1] * cA + fl[slot + 4 * B2 + 1] * cB;
      const float v2 = o0[4 * B2 + 2] * cA + fl[slot + 4 * B2 + 2] * cB;
      const float v3 = o0[4 * B2 + 3] * cA + fl[slot + 4 * B2 + 3] * cB;
      uint2 pv;
      pv.x = cvtpk(v0, v1);
      pv.y = cvtpk(v2, v3);
      *reinterpret_cast<uint2*>(orow + 8 * B2 + 4 * hi) = pv;
    }
#pragma unroll
    for (int B2 = 0; B2 < 4; ++B2) {
      const float v0 = o1[4 * B2 + 0] * cA + fl[slot + 16 + 4 * B2 + 0] * cB;
      const float v1 = o1[4 * B2 + 1] * cA + fl[slot + 16 + 4 * B2 + 1] * cB;
      const float v2 = o1[4 * B2 + 2] * cA + fl[slot + 16 + 4 * B2 + 2] * cB;
      const float v3 = o1[4 * B2 + 3] * cA + fl[slot + 16 + 4 * B2 + 3] * cB;
      uint2 pv;
      pv.x = cvtpk(v0, v1);
      pv.y = cvtpk(v2, v3);
      *reinterpret_cast<uint2*>(orow + 32 + 8 * B2 + 4 * hi) = pv;
    }
  }
}

extern "C" void kernel_launch(void* const* d_in, const int* in_sizes, int n_in,
                              void* d_out, int out_size, void* d_ws, size_t ws_size,
                              hipStream_t stream) {
  (void)in_sizes; (void)n_in; (void)out_size; (void)ws_size;
  const float* hidden = (const float*)d_in[0];
  const float* freqs = (const float*)d_in[1];
  const float* wq = (const float*)d_in[2];
  const float* wk = (const float*)d_in[3];
  const float* wv = (const float*)d_in[4];
  const float* wo = (const float*)d_in[5];
  float* out = (float*)d_out;

  char* ws = (char*)d_ws;
  const size_t MB8 = (size_t)Mrows * Dc * 2;  // 8 MiB
  const size_t WB = (size_t)Dc * Dc * 2;      // 2 MiB
  u16* hb = (u16*)ws;  ws += MB8;
  u16* wqb = (u16*)ws; ws += WB;
  u16* wkb = (u16*)ws; ws += WB;
  u16* wvb = (u16*)ws; ws += WB;
  u16* wob = (u16*)ws; ws += WB;
  u16* qb = (u16*)ws;  ws += MB8;
  u16* kb = (u16*)ws;  ws += MB8;
  u16* vtb = (u16*)ws; ws += MB8;
  u16* ab = (u16*)ws;  ws += MB8;

  cvt_all<<<8192, 256, 0, stream>>>(hidden, wq, wk, wv, wo, hb, wqb, wkb, wvb, wob);
  gemm_qkv<<<dim3(32, 24), 256, 0, stream>>>(hb, wqb, wkb, wvb, freqs, qb, kb, vtb);
  flash_attn<<<512, 512, 0, stream>>>(qb, kb, vtb, ab);
  gemm_out<<<dim3(64, 8), 256, 0, stream>>>(ab, wob, out);
}

// Round 23
// 126.777 us; speedup vs baseline: 1.0439x; 1.0314x over previous
//
#include <hip/hip_runtime.h>
#include <hip/hip_bf16.h>

typedef __attribute__((ext_vector_type(8))) short bf16x8;
typedef __attribute__((ext_vector_type(4))) float f32x4;
typedef __attribute__((ext_vector_type(16))) float f32x16;
typedef __attribute__((ext_vector_type(2))) float f32x2;
typedef unsigned short u16;

#define Bc   2
#define Sc   2048
#define Dc   1024
#define Hc   16
#define HDc  64
#define ROTc 32
#define Mrows 4096  // B*S

__device__ __forceinline__ u16 f2bf(float x) {
  union { float f; unsigned u; } v{x};
  unsigned r = v.u + 0x7fffu + ((v.u >> 16) & 1u);
  return (u16)(r >> 16);
}
__device__ __forceinline__ float bf2f(u16 x) {
  union { unsigned u; float f; } v{(unsigned)x << 16};
  return v.f;
}
__device__ __forceinline__ unsigned cvtpk(float a, float b) {
  unsigned r;
  asm("v_cvt_pk_bf16_f32 %0, %1, %2" : "=v"(r) : "v"(a), "v"(b));
  return r;
}
__device__ __forceinline__ f32x2 pmax2(f32x2 a, f32x2 b) {
  f32x2 r;
  r.x = fmaxf(a.x, b.x);
  r.y = fmaxf(a.y, b.y);
  return r;
}

__device__ __forceinline__ void gload_lds16(const void* g, void* l) {
  __builtin_amdgcn_global_load_lds(
      (const __attribute__((address_space(1))) void*)g,
      (__attribute__((address_space(3))) void*)l, 16, 0, 0);
}

// ---------------- f32 -> bf16 conversion (hidden + 4 weights in one grid) --
__global__ void cvt_all(const float* __restrict__ h, const float* __restrict__ q,
                        const float* __restrict__ k, const float* __restrict__ v,
                        const float* __restrict__ o,
                        u16* __restrict__ hb, u16* __restrict__ qb, u16* __restrict__ kb,
                        u16* __restrict__ vb, u16* __restrict__ ob) {
  size_t i = ((size_t)blockIdx.x * 256 + threadIdx.x) * 4;
  const float* s;
  u16* d;
  size_t off;
  if (i < (size_t)Mrows * Dc) {
    s = h; d = hb; off = i;
  } else {
    size_t j = i - (size_t)Mrows * Dc;
    int w = (int)(j >> 20);            // 1M elements per weight
    off = j & ((1u << 20) - 1);
    s = (w == 0) ? q : (w == 1) ? k : (w == 2) ? v : o;
    d = (w == 0) ? qb : (w == 1) ? kb : (w == 2) ? vb : ob;
  }
  float4 val = *reinterpret_cast<const float4*>(s + off);
  u16 r0 = f2bf(val.x), r1 = f2bf(val.y), r2 = f2bf(val.z), r3 = f2bf(val.w);
  ushort4 outv = {r0, r1, r2, r3};
  *reinterpret_cast<ushort4*>(d + off) = outv;
}

// ---------------- fused QKV NT GEMM + RoPE epilogue, BK=64, grid (32,24) --
// Best-known config (r19).  BK=64 halves barrier count vs BK=32; 32KB LDS
// keeps 3 blocks/CU.  Slot swizzle: row of 64 u16 = 8 slots of 16B; phys
// slot = logical ^ (row&7); staging keeps linear dest, SOURCE carries the
// inverse; reads apply the same XOR (rule 21).  Structure variants tried
// and rejected: dbuf (r15 null), 3-output fusion (r17 null), counted-vmcnt
// (r18 unsafe at source level), BK=128 (r22 -20%: blocks/CU 3->2 dominates).
__global__ void gemm_qkv(const u16* __restrict__ A, const u16* __restrict__ W0,
                         const u16* __restrict__ W1, const u16* __restrict__ W2,
                         const float* __restrict__ freqs,
                         u16* __restrict__ Qo, u16* __restrict__ Ko,
                         u16* __restrict__ Vo) {
  __shared__ u16 As[128 * 64];
  __shared__ u16 Bs[128 * 64];
  const int by = blockIdx.y;
  const int wsel = by >> 3;
  const int n0 = (by & 7) * 128;
  const int m0 = blockIdx.x * 128;
  const u16* Bm = (wsel == 0) ? W0 : (wsel == 1) ? W1 : W2;
  const int t = threadIdx.x;
  const int w = t >> 6;
  const int lane = t & 63;
  const int wm = w >> 1, wn = w & 1;
  const int c = lane & 15, g = lane >> 4;
  const int sr = t >> 3;
  const int skoff = ((t & 7) ^ (sr & 7)) * 8;

  f32x4 acc[4][4] = {};

  const u16* ag = A + (size_t)(m0 + sr) * Dc + skoff;
  const u16* bg = Bm + (size_t)(n0 + sr) * Dc + skoff;
  const int ldst = w * 512;  // wave-uniform base per site (u16)

  for (int k0 = 0; k0 < Dc; k0 += 64) {
#pragma unroll
    for (int site = 0; site < 4; ++site) {
      gload_lds16(ag + k0 + (size_t)(site * 32) * Dc, &As[site * 2048 + ldst]);
      gload_lds16(bg + k0 + (size_t)(site * 32) * Dc, &Bs[site * 2048 + ldst]);
    }
    __syncthreads();
#pragma unroll
    for (int sub = 0; sub < 2; ++sub) {
      bf16x8 a[4], b[4];
#pragma unroll
      for (int f = 0; f < 4; ++f) {
        const int row = wm * 64 + f * 16 + c;
        const int p = ((sub * 4 + g) ^ (c & 7)) * 8;
        a[f] = *(const bf16x8*)&As[row * 64 + p];
        const int rowb = wn * 64 + f * 16 + c;
        b[f] = *(const bf16x8*)&Bs[rowb * 64 + p];
      }
      __builtin_amdgcn_s_setprio(1);
#pragma unroll
      for (int fm = 0; fm < 4; ++fm)
#pragma unroll
        for (int fn = 0; fn < 4; ++fn)
          acc[fm][fn] =
              __builtin_amdgcn_mfma_f32_16x16x32_bf16(a[fm], b[fn], acc[fm][fn], 0, 0, 0);
      __builtin_amdgcn_s_setprio(0);
    }
    __syncthreads();
  }

  u16* dst = (wsel == 0) ? Qo : (wsel == 1) ? Ko : Vo;
  const float qsc = (wsel == 0) ? 0.125f * 1.44269504f : 1.0f;  // HD^-0.5*log2e
  const int codd = c & 1;
#pragma unroll
  for (int fm = 0; fm < 4; ++fm)
#pragma unroll
    for (int fn = 0; fn < 4; ++fn)
#pragma unroll
      for (int r = 0; r < 4; ++r) {
        const int m = m0 + wm * 64 + fm * 16 + g * 4 + r;
        const int n = n0 + wn * 64 + fn * 16 + c;
        float v = acc[fm][fn][r];
        const int b = m >> 11, s = m & (Sc - 1);
        const int hh = n >> 6, d = n & 63;
        size_t idx2;
        if (wsel < 2) {
          const float other = __shfl_xor(v, 1);
          const float2 f = reinterpret_cast<const float2*>(freqs)[s * ROTc + (d >> 1)];
          v = codd ? (v * f.x + other * f.y) : (v * f.x - other * f.y);
          v *= qsc;
          idx2 = (((size_t)(b * Hc + hh) * Sc) + s) * HDc + d;
        } else {
          idx2 = ((size_t)(b * Hc + hh) * HDc + d) * Sc + s;
        }
        dst[idx2] = f2bf(v);
      }
}

// ---------------- final GEMM: out = ab @ wo^T, BK=64, grid (64,8) ---------
__global__ void gemm_out(const u16* __restrict__ A, const u16* __restrict__ Bm,
                         float* __restrict__ C) {
  __shared__ u16 As[64 * 64];
  __shared__ u16 Bs[128 * 64];
  const int m0 = blockIdx.x * 64;
  const int n0 = blockIdx.y * 128;
  const int t = threadIdx.x;
  const int w = t >> 6;
  const int lane = t & 63;
  const int wm = w >> 1, wn = w & 1;  // wave tile 32x64
  const int c = lane & 15, g = lane >> 4;
  const int sr = t >> 3;
  const int skoff = ((t & 7) ^ (sr & 7)) * 8;

  f32x4 acc[2][4] = {};

  const u16* ag = A + (size_t)(m0 + sr) * Dc + skoff;
  const u16* bg = Bm + (size_t)(n0 + sr) * Dc + skoff;
  const int ldst = w * 512;

  for (int k0 = 0; k0 < Dc; k0 += 64) {
#pragma unroll
    for (int site = 0; site < 2; ++site)
      gload_lds16(ag + k0 + (size_t)(site * 32) * Dc, &As[site * 2048 + ldst]);
#pragma unroll
    for (int site = 0; site < 4; ++site)
      gload_lds16(bg + k0 + (size_t)(site * 32) * Dc, &Bs[site * 2048 + ldst]);
    __syncthreads();
#pragma unroll
    for (int sub = 0; sub < 2; ++sub) {
      bf16x8 a[2], b[4];
      const int p = ((sub * 4 + g) ^ (c & 7)) * 8;
#pragma unroll
      for (int f = 0; f < 2; ++f)
        a[f] = *(const bf16x8*)&As[(wm * 32 + f * 16 + c) * 64 + p];
#pragma unroll
      for (int f = 0; f < 4; ++f)
        b[f] = *(const bf16x8*)&Bs[(wn * 64 + f * 16 + c) * 64 + p];
      __builtin_amdgcn_s_setprio(1);
#pragma unroll
      for (int fm = 0; fm < 2; ++fm)
#pragma unroll
        for (int fn = 0; fn < 4; ++fn)
          acc[fm][fn] =
              __builtin_amdgcn_mfma_f32_16x16x32_bf16(a[fm], b[fn], acc[fm][fn], 0, 0, 0);
      __builtin_amdgcn_s_setprio(0);
    }
    __syncthreads();
  }

#pragma unroll
  for (int fm = 0; fm < 2; ++fm)
#pragma unroll
    for (int fn = 0; fn < 4; ++fn)
#pragma unroll
      for (int r = 0; r < 4; ++r) {
        const int m = m0 + wm * 32 + fm * 16 + g * 4 + r;
        const int n = n0 + wn * 64 + fn * 16 + c;
        C[(size_t)m * Dc + n] = acc[fm][fn][r];
      }
}

// ---------------- flash attention: in-block split-KV (r13/r19 proven) -----
// 512 thr = 2 groups x 4 waves; group g covers kv [g*1024, (g+1)*1024).
// Grid 512 = 2 blocks/CU.  Single K/V buffer per group, in-LDS LSE merge.
// Rejected variants: global split-KV (r8 -16%), sw pipeline (r11 null),
// 64-q blocks (r20 -10%), LDS shrink (r16 null: grid-capped).
// v_permlane32_swap BANNED (r5+r10); all exchanges via __shfl_xor.
__global__ __launch_bounds__(512, 2) void flash_attn(
    const u16* __restrict__ Q, const u16* __restrict__ Kb,
    const u16* __restrict__ Vt, u16* __restrict__ Ob) {
  __shared__ u16 smem[18432];  // K: grp*4096 ; V: 8192+grp*4096 ; 36KB total
  const int orig = blockIdx.x;
  const int wg = (orig & 7) * 64 + (orig >> 3);  // bijective XCD chunking
  const int bh = wg >> 4;
  const int q0 = (wg & 15) * 128;
  const int t = threadIdx.x, w = t >> 6, lane = t & 63;
  const int grp = w >> 2, wl = w & 3;
  const int ts = t & 255;  // thread index within group
  const int l31 = lane & 31, hi = lane >> 5;
  const int sr = ts >> 4;
  const int su = (ts & 15) ^ (sr & 15);
  const int skv = sr + ((su >> 3) << 5);  // source kv (K) / d (V) row
  const int sd8 = (su & 7) * 8;           // source col offset (u16)
  const int rsw = (l31 & 15);             // read-side slot swizzle

  const u16* Qp = Q + (size_t)bh * Sc * HDc;
  const u16* Kp = Kb + (size_t)bh * Sc * HDc;
  const u16* Vp = Vt + (size_t)bh * HDc * Sc;
  u16* const Kg = smem + grp * 4096;
  u16* const Vg = smem + 8192 + grp * 4096;

  const int q = q0 + wl * 32 + l31;
  bf16x8 aq[4];
#pragma unroll
  for (int kd = 0; kd < 4; ++kd)
    aq[kd] = *(const bf16x8*)(Qp + (size_t)q * HDc + kd * 16 + hi * 8);

  float m_run = -1e30f, l_run = 0.f;
  f32x16 o0 = {}, o1 = {};

  auto STAGE = [&](int tile) {
    const int base = grp * 1024 + tile * 64;
    gload_lds16(Kp + (size_t)(base + skv) * HDc + sd8, Kg + wl * 512);
    gload_lds16(Kp + (size_t)(base + skv + 16) * HDc + sd8, Kg + 2048 + wl * 512);
    gload_lds16(Vp + (size_t)skv * Sc + base + sd8, Vg + wl * 512);
    gload_lds16(Vp + (size_t)(skv + 16) * Sc + base + sd8, Vg + 2048 + wl * 512);
  };

  for (int tt = 0; tt < 16; ++tt) {
    STAGE(tt);
    __syncthreads();  // stage landed (barrier drains vmcnt)
    f32x16 s0 = {}, s1 = {};
    __builtin_amdgcn_s_setprio(1);
#pragma unroll
    for (int kd = 0; kd < 4; ++kd) {
      const int u0 = kd * 2 + hi;
      bf16x8 a0 = *(const bf16x8*)&Kg[l31 * 128 + (u0 ^ rsw) * 8];
      bf16x8 a1 = *(const bf16x8*)&Kg[l31 * 128 + ((u0 + 8) ^ rsw) * 8];
      s0 = __builtin_amdgcn_mfma_f32_32x32x16_bf16(a0, aq[kd], s0, 0, 0, 0);
      s1 = __builtin_amdgcn_mfma_f32_32x32x16_bf16(a1, aq[kd], s1, 0, 0, 0);
    }
    __builtin_amdgcn_s_setprio(0);
    f32x2 t4[4];
#pragma unroll
    for (int i = 0; i < 4; ++i) {
      f32x2 e0; e0.x = s0[2 * i]; e0.y = s0[2 * i + 1];
      f32x2 e1; e1.x = s0[2 * i + 8]; e1.y = s0[2 * i + 9];
      f32x2 e2; e2.x = s1[2 * i]; e2.y = s1[2 * i + 1];
      f32x2 e3; e3.x = s1[2 * i + 8]; e3.y = s1[2 * i + 9];
      t4[i] = pmax2(pmax2(e0, e1), pmax2(e2, e3));
    }
    f32x2 tp = pmax2(pmax2(t4[0], t4[1]), pmax2(t4[2], t4[3]));
    float mt = fmaxf(tp.x, tp.y);
    mt = fmaxf(mt, __shfl_xor(mt, 32));
    const bool skip = __all(mt <= m_run + 8.0f);
    if (!skip) {
      const float mn2 = fmaxf(m_run, mt);
      const float scl = __builtin_amdgcn_exp2f(m_run - mn2);
      m_run = mn2;
      l_run *= scl;
      o0 *= scl;
      o1 *= scl;
    }
    const float mn = m_run;
#pragma unroll
    for (int r = 0; r < 16; ++r) {
      s0[r] = __builtin_amdgcn_exp2f(s0[r] - mn);
      s1[r] = __builtin_amdgcn_exp2f(s1[r] - mn);
    }
    f32x2 ac;
    ac.x = 0.f; ac.y = 0.f;
#pragma unroll
    for (int i = 0; i < 8; ++i) {
      f32x2 e0; e0.x = s0[2 * i]; e0.y = s0[2 * i + 1];
      f32x2 e1; e1.x = s1[2 * i]; e1.y = s1[2 * i + 1];
      ac += e0 + e1;
    }
    float rs = ac.x + ac.y;
    rs += __shfl_xor(rs, 32);
    l_run += rs;
    unsigned pk0[8], pk1[8];
#pragma unroll
    for (int B = 0; B < 4; ++B)
#pragma unroll
      for (int s2 = 0; s2 < 2; ++s2) {
        pk0[B * 2 + s2] = cvtpk(s0[4 * B + 2 * s2], s0[4 * B + 2 * s2 + 1]);
        pk1[B * 2 + s2] = cvtpk(s1[4 * B + 2 * s2], s1[4 * B + 2 * s2 + 1]);
      }
#pragma unroll
    for (int ks = 0; ks < 4; ++ks) {
      const unsigned* pk = (ks >> 1) ? pk1 : pk0;
      const int m2 = (ks & 1) * 4;
      const unsigned A0 = pk[m2 + 0], A1 = pk[m2 + 1];
      const unsigned B0 = pk[m2 + 2], B1 = pk[m2 + 3];
      const unsigned L0 = hi ? B0 : A0, L1 = hi ? B1 : A1;
      const unsigned R0 = hi ? A0 : B0, R1 = hi ? A1 : B1;
      const unsigned X0 = __shfl_xor(R0, 32), X1 = __shfl_xor(R1, 32);
      union { unsigned u[4]; bf16x8 v; } bp;
      bp.u[0] = hi ? X0 : L0;
      bp.u[1] = hi ? X1 : L1;
      bp.u[2] = hi ? L0 : X0;
      bp.u[3] = hi ? L1 : X1;
      const int uv = ks * 2 + hi;
      bf16x8 va0 = *(const bf16x8*)&Vg[l31 * 128 + (uv ^ rsw) * 8];
      bf16x8 va1 = *(const bf16x8*)&Vg[l31 * 128 + ((uv + 8) ^ rsw) * 8];
      __builtin_amdgcn_s_setprio(1);
      o0 = __builtin_amdgcn_mfma_f32_32x32x16_bf16(va0, bp.v, o0, 0, 0, 0);
      o1 = __builtin_amdgcn_mfma_f32_32x32x16_bf16(va1, bp.v, o1, 0, 0, 0);
      __builtin_amdgcn_s_setprio(0);
    }
    __syncthreads();  // all reads of this tile done before next stage
  }

  // ---- in-LDS merge: group 1 -> LDS (raw O + m + l), group 0 combines ----
  float* fl = reinterpret_cast<float*>(smem);
  const int slot = (wl * 64 + lane) * 34;
  if (grp == 1) {
#pragma unroll
    for (int j = 0; j < 16; ++j) fl[slot + j] = o0[j];
#pragma unroll
    for (int j = 0; j < 16; ++j) fl[slot + 16 + j] = o1[j];
    fl[slot + 32] = m_run;
    fl[slot + 33] = l_run;
  }
  __syncthreads();
  if (grp == 0) {
    const float mB = fl[slot + 32], lB = fl[slot + 33];
    const float mx = fmaxf(m_run, mB);
    const float sA = __builtin_amdgcn_exp2f(m_run - mx);
    const float sB = __builtin_amdgcn_exp2f(mB - mx);
    const float rd = 1.0f / (l_run * sA + lB * sB);
    const float cA = sA * rd, cB = sB * rd;
    const int b = bh >> 4, hh = bh & 15;
    u16* orow = Ob + ((size_t)b * Sc + q) * Dc + hh * HDc;
#pragma unroll
    for (int B2 = 0; B2 < 4; ++B2) {
      const float v0 = o0[4 * B2 + 0] * cA + fl[slot + 4 * B2 + 0] * cB;
      const float v1 = o0[4 * B2 + 1] * cA + fl[slot + 4 * B2 + 1] * cB;
      const float v2 = o0[4 * B2 + 2] * cA + fl[slot + 4 * B2 + 2] * cB;
      const float v3 = o0[4 * B2 + 3] * cA + fl[slot + 4 * B2 + 3] * cB;
      uint2 pv;
      pv.x = cvtpk(v0, v1);
      pv.y = cvtpk(v2, v3);
      *reinterpret_cast<uint2*>(orow + 8 * B2 + 4 * hi) = pv;
    }
#pragma unroll
    for (int B2 = 0; B2 < 4; ++B2) {
      const float v0 = o1[4 * B2 + 0] * cA + fl[slot + 16 + 4 * B2 + 0] * cB;
      const float v1 = o1[4 * B2 + 1] * cA + fl[slot + 16 + 4 * B2 + 1] * cB;
      const float v2 = o1[4 * B2 + 2] * cA + fl[slot + 16 + 4 * B2 + 2] * cB;
      const float v3 = o1[4 * B2 + 3] * cA + fl[slot + 16 + 4 * B2 + 3] * cB;
      uint2 pv;
      pv.x = cvtpk(v0, v1);
      pv.y = cvtpk(v2, v3);
      *reinterpret_cast<uint2*>(orow + 32 + 8 * B2 + 4 * hi) = pv;
    }
  }
}

extern "C" void kernel_launch(void* const* d_in, const int* in_sizes, int n_in,
                              void* d_out, int out_size, void* d_ws, size_t ws_size,
                              hipStream_t stream) {
  (void)in_sizes; (void)n_in; (void)out_size; (void)ws_size;
  const float* hidden = (const float*)d_in[0];
  const float* freqs = (const float*)d_in[1];
  const float* wq = (const float*)d_in[2];
  const float* wk = (const float*)d_in[3];
  const float* wv = (const float*)d_in[4];
  const float* wo = (const float*)d_in[5];
  float* out = (float*)d_out;

  char* ws = (char*)d_ws;
  const size_t MB8 = (size_t)Mrows * Dc * 2;  // 8 MiB
  const size_t WB = (size_t)Dc * Dc * 2;      // 2 MiB
  u16* hb = (u16*)ws;  ws += MB8;
  u16* wqb = (u16*)ws; ws += WB;
  u16* wkb = (u16*)ws; ws += WB;
  u16* wvb = (u16*)ws; ws += WB;
  u16* wob = (u16*)ws; ws += WB;
  u16* qb = (u16*)ws;  ws += MB8;
  u16* kb = (u16*)ws;  ws += MB8;
  u16* vtb = (u16*)ws; ws += MB8;
  u16* ab = (u16*)ws;  ws += MB8;

  cvt_all<<<8192, 256, 0, stream>>>(hidden, wq, wk, wv, wo, hb, wqb, wkb, wvb, wob);
  gemm_qkv<<<dim3(32, 24), 256, 0, stream>>>(hb, wqb, wkb, wvb, freqs, qb, kb, vtb);
  flash_attn<<<512, 512, 0, stream>>>(qb, kb, vtb, ab);
  gemm_out<<<dim3(64, 8), 256, 0, stream>>>(ab, wob, out);
}